// Round 8
// baseline (13.373 us; speedup 1.0000x reference)
//
#include <hip/hip_runtime.h>
#include <math.h>

#define B_ROWS 8192
#define D_DIM 512
#define N_LABELS 256
#define GMAX 64              // max group size on MFMA path (P[exceed] ~ 1e-8; exact fallback below)
#define THREADS 1024
#define WAVES 16
#define SEG (B_ROWS / WAVES) // 512 rows scanned per wave
#define SITER (SEG / 64)     // 8 ballot iterations per wave
#define LSTRIDE (D_DIM + 8)  // 520 fp16 per row -> 1040 B stride (16B-aligned, 2-way bank alias only)

typedef __attribute__((ext_vector_type(8))) _Float16 f16x8;
typedef __attribute__((ext_vector_type(4))) float f32x4;

static __device__ __forceinline__ unsigned short f2h(float f) {
    const _Float16 h = (_Float16)f;       // v_cvt_f16_f32 (RNE)
    return __builtin_bit_cast(unsigned short, h);
}
static __device__ __forceinline__ float h2f(unsigned short u) {
    return (float)__builtin_bit_cast(_Float16, u);
}

// One block per label; 16 waves; single fused kernel, 4 barriers total.
// P1: ballot-scan Mx (masks stay in registers) -> per-wave counts.
// P2: 16-lane shfl prefix -> wbase/cnt.
// P3: PER-WAVE fused scatter+stage: each wave writes its own rows' ids, fp16
//     LDS copy, and fp32 |z_h|^2 -- gather addresses come from registers, no
//     ids_sh dependency, starts one barrier earlier than before.
// P4: MFMA fp16 gram, upper-triangle tiles, one tile per wave (no barrier
//     after MFMA: sq_sh was written in P3).
// P5: distance epilogue (row sums + off-diag column sums), final reduce.
__global__ __launch_bounds__(THREADS) void loss_kernel(const float* __restrict__ z,
                                                       const int* __restrict__ Mx,
                                                       float* __restrict__ out) {
    __shared__ __align__(16) unsigned short h_sh[GMAX][LSTRIDE];  // 66,560 B
    __shared__ int   ids_sh[GMAX];
    __shared__ float sq_sh[GMAX];
    __shared__ float rowpart[WAVES][GMAX];                        // 4 KB
    __shared__ int   wcnt[WAVES], wbase[WAVES];
    __shared__ int   cnt_sh;

    const int lbl  = blockIdx.x;
    const int tid  = threadIdx.x;
    const int wv   = tid >> 6;
    const int lane = tid & 63;
    const int sb   = wv * SEG;

    // ---- P1: ballot scan; masks kept in registers (wave-uniform) ----
    unsigned long long bal[SITER];
    int c = 0;
    #pragma unroll
    for (int t = 0; t < SITER; ++t) {
        bal[t] = __ballot(Mx[sb + t * 64 + lane] == lbl);
        c += __popcll(bal[t]);
    }
    if (lane == 0) wcnt[wv] = c;
    for (int i = tid; i < WAVES * GMAX; i += THREADS) ((float*)rowpart)[i] = 0.f;
    __syncthreads();                                   // B1

    // ---- P2: parallel 16-lane inclusive scan in wave 0 ----
    if (wv == 0) {
        int v = (lane < WAVES) ? wcnt[lane] : 0;
        #pragma unroll
        for (int d = 1; d < WAVES; d <<= 1) {
            const int o = __shfl_up(v, d, 64);
            if (lane >= d) v += o;
        }
        if (lane < WAVES) wbase[lane] = v - wcnt[lane];
        if (lane == WAVES - 1) cnt_sh = v;
    }
    __syncthreads();                                   // B2
    const int cnt = cnt_sh;
    if (cnt <= 0) return;

    if (cnt > GMAX) {
        // exact fp32 fallback (statistically never runs; correctness guard)
        int k = 0;
        for (int i = 0; i < B_ROWS; ++i) {
            if (Mx[i] != lbl) continue;
            if ((k++ % WAVES) != wv) continue;
            float acc2 = 0.f;
            for (int j = 0; j < B_ROWS; ++j) {
                if (Mx[j] != lbl || j == i) continue;
                float s = 0.f;
                for (int d = lane; d < D_DIM; d += 64) {
                    const float t = z[(size_t)i * D_DIM + d] - z[(size_t)j * D_DIM + d];
                    s = fmaf(t, t, s);
                }
                s += __shfl_xor(s, 1, 64);
                s += __shfl_xor(s, 2, 64);
                s += __shfl_xor(s, 4, 64);
                s += __shfl_xor(s, 8, 64);
                s += __shfl_xor(s, 16, 64);
                s += __shfl_xor(s, 32, 64);
                acc2 += (s > 0.f) ? sqrtf(s) : 0.f;
            }
            if (lane == 0) out[i] = acc2 / (float)(cnt - 1);
        }
        return;
    }

    // ---- P3: per-wave fused scatter + fp16 staging + |z_h|^2 ----
    {
        int pos = wbase[wv];
        #pragma unroll
        for (int t = 0; t < SITER; ++t) {
            unsigned long long m = bal[t];
            while (m) {                                  // wave-uniform loop
                const int b = __ffsll((long long)m) - 1;
                m &= m - 1;
                const int row = sb + t * 64 + b;
                const float* __restrict__ zp = z + (size_t)row * D_DIM + lane * 8;
                const float4 v0 = *(const float4*)(zp);
                const float4 v1 = *(const float4*)(zp + 4);
                const unsigned short e0 = f2h(v0.x), e1 = f2h(v0.y), e2 = f2h(v0.z), e3 = f2h(v0.w);
                const unsigned short e4 = f2h(v1.x), e5 = f2h(v1.y), e6 = f2h(v1.z), e7 = f2h(v1.w);
                uint4 pk;
                pk.x = (unsigned int)e0 | ((unsigned int)e1 << 16);
                pk.y = (unsigned int)e2 | ((unsigned int)e3 << 16);
                pk.z = (unsigned int)e4 | ((unsigned int)e5 << 16);
                pk.w = (unsigned int)e6 | ((unsigned int)e7 << 16);
                *(uint4*)&h_sh[pos][lane * 8] = pk;

                // fp32 sum of exact fp16 squares (consistent with MFMA products)
                float sp = h2f(e0) * h2f(e0);
                sp = fmaf(h2f(e1), h2f(e1), sp);
                sp = fmaf(h2f(e2), h2f(e2), sp);
                sp = fmaf(h2f(e3), h2f(e3), sp);
                sp = fmaf(h2f(e4), h2f(e4), sp);
                sp = fmaf(h2f(e5), h2f(e5), sp);
                sp = fmaf(h2f(e6), h2f(e6), sp);
                sp = fmaf(h2f(e7), h2f(e7), sp);
                sp += __shfl_xor(sp, 1, 64);
                sp += __shfl_xor(sp, 2, 64);
                sp += __shfl_xor(sp, 4, 64);
                sp += __shfl_xor(sp, 8, 64);
                sp += __shfl_xor(sp, 16, 64);
                sp += __shfl_xor(sp, 32, 64);
                if (lane == 0) {
                    ids_sh[pos] = row;
                    sq_sh[pos]  = sp;
                }
                ++pos;
            }
        }
    }
    __syncthreads();                                   // B3

    // ---- P4: MFMA fp16 gram, upper-triangle tiles, one tile per wave ----
    const int NT = (cnt + 15) >> 4;           // 1..4
    const int TS = NT * (NT + 1) / 2;         // 1,3,6,10

    int jt = 0;
    #pragma unroll
    for (int q = 1; q < 4; ++q) jt += (wv >= q * (q + 1) / 2);  // wv -> (it,jt) col-major tri
    const int it = wv - jt * (jt + 1) / 2;
    const bool own = (wv < TS);

    const int l15 = lane & 15;
    const int lh  = lane >> 4;                // 0..3

    f32x4 acc = {0.f, 0.f, 0.f, 0.f};
    if (own) {
        #pragma unroll
        for (int k4 = 0; k4 < D_DIM / 32; ++k4) {
            const int kb = k4 * 32 + lh * 8;
            const f16x8 a = *(const f16x8*)&h_sh[it * 16 + l15][kb];
            const f16x8 b = *(const f16x8*)&h_sh[jt * 16 + l15][kb];
            acc = __builtin_amdgcn_mfma_f32_16x16x32_f16(a, b, acc, 0, 0, 0);
        }
    }
    // no barrier: sq_sh already valid since B3; acc is in registers

    // ---- P5: distances; row sums + (off-diag) column sums ----
    // C/D layout (m89-verified): col = lane&15, row = (lane>>4)*4 + reg
    if (own) {
        float d0 = 0.f, d1 = 0.f, d2v = 0.f, d3 = 0.f;
        #pragma unroll
        for (int r = 0; r < 4; ++r) {
            const int gi = it * 16 + lh * 4 + r;
            const int gj = jt * 16 + l15;
            const float d2 = sq_sh[gi] + sq_sh[gj] - 2.f * acc[r];
            const bool valid = (gi < cnt) && (gj < cnt) && (gi != gj) && (d2 > 0.f);
            const float dist = valid ? sqrtf(d2) : 0.f;
            if (r == 0) d0 = dist; else if (r == 1) d1 = dist; else if (r == 2) d2v = dist; else d3 = dist;

            float rs = dist;
            rs += __shfl_xor(rs, 1, 64);
            rs += __shfl_xor(rs, 2, 64);
            rs += __shfl_xor(rs, 4, 64);
            rs += __shfl_xor(rs, 8, 64);
            if (l15 == 0) rowpart[wv][gi] += rs;
        }
        if (it != jt) {
            float cs = (d0 + d1) + (d2v + d3);  // sum over this lane's 4 rows
            cs += __shfl_xor(cs, 16, 64);
            cs += __shfl_xor(cs, 32, 64);       // sum over all 16 rows of the tile
            if (lane < 16) rowpart[wv][jt * 16 + l15] += cs;
        }
    }
    __syncthreads();                                   // B4

    // ---- final reduce over waves + write ----
    if (tid < cnt) {
        float s = 0.f;
        #pragma unroll
        for (int w = 0; w < WAVES; ++w) s += rowpart[w][tid];
        out[ids_sh[tid]] = (cnt > 1) ? s / (float)(cnt - 1) : 0.f;
    }
}

// ---------------- launch ----------------
extern "C" void kernel_launch(void* const* d_in, const int* in_sizes, int n_in,
                              void* d_out, int out_size, void* d_ws, size_t ws_size,
                              hipStream_t stream) {
    const float* z  = (const float*)d_in[0];
    const int*   Mx = (const int*)d_in[1];
    float*       out = (float*)d_out;

    loss_kernel<<<N_LABELS, THREADS, 0, stream>>>(z, Mx, out);
}

// Round 9
// 11.079 us; speedup vs baseline: 1.2071x; 1.2071x over previous
//
#include <hip/hip_runtime.h>
#include <math.h>

#define B_ROWS 8192
#define D_DIM 512
#define N_LABELS 256
#define GMAX 64              // max group size on MFMA path (P[exceed] ~ 1e-8; exact fallback below)
#define THREADS 1024
#define WAVES 16
#define SEG (B_ROWS / WAVES) // 512 rows scanned per wave
#define SITER (SEG / 64)     // 8 ballot iterations per wave
#define LSTRIDE (D_DIM + 8)  // 520 fp16 per row -> 1040 B stride (16B-aligned, 2-way bank alias only)

typedef __attribute__((ext_vector_type(8))) _Float16 f16x8;
typedef __attribute__((ext_vector_type(4))) float f32x4;

static __device__ __forceinline__ unsigned short f2h(float f) {
    const _Float16 h = (_Float16)f;       // v_cvt_f16_f32 (RNE)
    return __builtin_bit_cast(unsigned short, h);
}

// One block per label; 16 waves; single fused kernel (round-7 structure, best
// measured at 12.94 us; round-8's per-wave serial staging regressed and was
// reverted).
// P1 : ballot-scan Mx once, masks kept in REGISTERS; rowpart zeroed here.
// P2 : 16-lane shfl prefix -> wbase/cnt.
// P1b: per-wave stable rank scatter of ids from register masks (no LDS masks).
// P3 : fully-distributed staging pass, fp32 -> fp16 LDS (all 1024 threads).
// P4 : MFMA fp16 gram, upper-triangle tiles, one 16x16 tile per wave.
// P4a: gram diagonal -> |z_h|^2 (consistent quantization).
// P4b: distances; row sums + off-diag column sums; final reduce.
__global__ __launch_bounds__(THREADS) void loss_kernel(const float* __restrict__ z,
                                                       const int* __restrict__ Mx,
                                                       float* __restrict__ out) {
    __shared__ __align__(16) unsigned short h_sh[GMAX][LSTRIDE];  // 66,560 B
    __shared__ int   ids_sh[GMAX];
    __shared__ float sq_sh[GMAX];
    __shared__ float rowpart[WAVES][GMAX];                        // 4 KB
    __shared__ int   wcnt[WAVES], wbase[WAVES];
    __shared__ int   cnt_sh;

    const int lbl  = blockIdx.x;
    const int tid  = threadIdx.x;
    const int wv   = tid >> 6;
    const int lane = tid & 63;
    const int sb   = wv * SEG;

    // ---- P1: ballot scan; masks stay in registers (wave-uniform) ----
    unsigned long long bal[SITER];
    int c = 0;
    #pragma unroll
    for (int t = 0; t < SITER; ++t) {
        bal[t] = __ballot(Mx[sb + t * 64 + lane] == lbl);
        c += __popcll(bal[t]);
    }
    if (lane == 0) wcnt[wv] = c;
    for (int i = tid; i < WAVES * GMAX; i += THREADS) ((float*)rowpart)[i] = 0.f;
    __syncthreads();                                   // B1

    // ---- P2: parallel 16-lane inclusive scan in wave 0 ----
    if (wv == 0) {
        int v = (lane < WAVES) ? wcnt[lane] : 0;
        #pragma unroll
        for (int d = 1; d < WAVES; d <<= 1) {
            const int o = __shfl_up(v, d, 64);
            if (lane >= d) v += o;
        }
        if (lane < WAVES) wbase[lane] = v - wcnt[lane];
        if (lane == WAVES - 1) cnt_sh = v;
    }
    __syncthreads();                                   // B2
    const int cnt = cnt_sh;
    if (cnt <= 0) return;

    if (cnt > GMAX) {
        // exact fp32 fallback (statistically never runs; correctness guard)
        int k = 0;
        for (int i = 0; i < B_ROWS; ++i) {
            if (Mx[i] != lbl) continue;
            if ((k++ % WAVES) != wv) continue;
            float acc2 = 0.f;
            for (int j = 0; j < B_ROWS; ++j) {
                if (Mx[j] != lbl || j == i) continue;
                float s = 0.f;
                for (int d = lane; d < D_DIM; d += 64) {
                    const float t = z[(size_t)i * D_DIM + d] - z[(size_t)j * D_DIM + d];
                    s = fmaf(t, t, s);
                }
                s += __shfl_xor(s, 1, 64);
                s += __shfl_xor(s, 2, 64);
                s += __shfl_xor(s, 4, 64);
                s += __shfl_xor(s, 8, 64);
                s += __shfl_xor(s, 16, 64);
                s += __shfl_xor(s, 32, 64);
                acc2 += (s > 0.f) ? sqrtf(s) : 0.f;
            }
            if (lane == 0) out[i] = acc2 / (float)(cnt - 1);
        }
        return;
    }

    // ---- P1b: stable rank scatter of ids from register masks ----
    {
        int pos = wbase[wv];
        const unsigned long long lower = (lane == 0) ? 0ull : ((1ull << lane) - 1ull);
        #pragma unroll
        for (int t = 0; t < SITER; ++t) {
            const unsigned long long b = bal[t];
            if ((b >> lane) & 1ull)
                ids_sh[pos + __popcll(b & lower)] = sb + t * 64 + lane;
            pos += __popcll(b);
        }
    }
    __syncthreads();                                   // B3

    // ---- P3: fully-distributed staging pass, fp32 -> fp16 ----
    for (int c2 = tid; c2 < cnt * (D_DIM / 4); c2 += THREADS) {
        const int row = c2 >> 7;              // D_DIM/4 == 128
        const int c4  = c2 & 127;
        const float4 v = *(const float4*)(z + (size_t)ids_sh[row] * D_DIM + c4 * 4);
        const unsigned int p0 = (unsigned int)f2h(v.x) | ((unsigned int)f2h(v.y) << 16);
        const unsigned int p1 = (unsigned int)f2h(v.z) | ((unsigned int)f2h(v.w) << 16);
        *(uint2*)&h_sh[row][c4 * 4] = make_uint2(p0, p1);
    }
    __syncthreads();                                   // B4

    // ---- P4: MFMA fp16 gram, upper-triangle tiles, one tile per wave ----
    const int NT = (cnt + 15) >> 4;           // 1..4
    const int TS = NT * (NT + 1) / 2;         // 1,3,6,10

    int jt = 0;
    #pragma unroll
    for (int q = 1; q < 4; ++q) jt += (wv >= q * (q + 1) / 2);  // wv -> (it,jt) col-major tri
    const int it = wv - jt * (jt + 1) / 2;
    const bool own = (wv < TS);

    const int l15 = lane & 15;
    const int lh  = lane >> 4;                // 0..3

    f32x4 acc = {0.f, 0.f, 0.f, 0.f};
    if (own) {
        #pragma unroll
        for (int k4 = 0; k4 < D_DIM / 32; ++k4) {
            const int kb = k4 * 32 + lh * 8;
            const f16x8 a = *(const f16x8*)&h_sh[it * 16 + l15][kb];
            const f16x8 b = *(const f16x8*)&h_sh[jt * 16 + l15][kb];
            acc = __builtin_amdgcn_mfma_f32_16x16x32_f16(a, b, acc, 0, 0, 0);
        }
    }

    // ---- P4a: gram diagonal = |z_h|^2 (diagonal tiles only) ----
    // C/D layout (m89-verified): col = lane&15, row = (lane>>4)*4 + reg
    if (own && it == jt) {
        #pragma unroll
        for (int r = 0; r < 4; ++r) {
            const int drow = lh * 4 + r;
            if (l15 == drow) sq_sh[it * 16 + drow] = acc[r];
        }
    }
    __syncthreads();                                   // B5

    // ---- P4b: distances; row sums + (off-diag) column sums ----
    if (own) {
        float d0 = 0.f, d1 = 0.f, d2v = 0.f, d3 = 0.f;
        #pragma unroll
        for (int r = 0; r < 4; ++r) {
            const int gi = it * 16 + lh * 4 + r;
            const int gj = jt * 16 + l15;
            const float d2 = sq_sh[gi] + sq_sh[gj] - 2.f * acc[r];
            const bool valid = (gi < cnt) && (gj < cnt) && (gi != gj) && (d2 > 0.f);
            const float dist = valid ? sqrtf(d2) : 0.f;
            if (r == 0) d0 = dist; else if (r == 1) d1 = dist; else if (r == 2) d2v = dist; else d3 = dist;

            float rs = dist;
            rs += __shfl_xor(rs, 1, 64);
            rs += __shfl_xor(rs, 2, 64);
            rs += __shfl_xor(rs, 4, 64);
            rs += __shfl_xor(rs, 8, 64);
            if (l15 == 0) rowpart[wv][gi] += rs;
        }
        if (it != jt) {
            float cs = (d0 + d1) + (d2v + d3);  // sum over this lane's 4 rows
            cs += __shfl_xor(cs, 16, 64);
            cs += __shfl_xor(cs, 32, 64);       // sum over all 16 rows of the tile
            if (lane < 16) rowpart[wv][jt * 16 + l15] += cs;
        }
    }
    __syncthreads();                                   // B6

    // ---- final reduce over waves + write ----
    if (tid < cnt) {
        float s = 0.f;
        #pragma unroll
        for (int w = 0; w < WAVES; ++w) s += rowpart[w][tid];
        out[ids_sh[tid]] = (cnt > 1) ? s / (float)(cnt - 1) : 0.f;
    }
}

// ---------------- launch ----------------
extern "C" void kernel_launch(void* const* d_in, const int* in_sizes, int n_in,
                              void* d_out, int out_size, void* d_ws, size_t ws_size,
                              hipStream_t stream) {
    const float* z  = (const float*)d_in[0];
    const int*   Mx = (const int*)d_in[1];
    float*       out = (float*)d_out;

    loss_kernel<<<N_LABELS, THREADS, 0, stream>>>(z, Mx, out);
}